// Round 1
// baseline (1521.538 us; speedup 1.0000x reference)
//
#include <hip/hip_runtime.h>
#include <hip/hip_bf16.h>

// Problem constants
#define BB 4
#define H_ 128
#define W_ 128
#define HWP 16384   // 128*128
#define CIN1 64
#define CMID 128
#define COUT 128
#define KOFF 18     // 2*K offset channels

// ---- workspace layout (float offsets) ----
// [0]           : dtype flag (int)
// [16..271]     : BN scale/shift (a[128], b[128])
// [288..]       : converted fp32 inputs (4,447,396 floats)
// then W1T, W2T, OFF, Y1, Y2
#define WS_AB      16
#define WS_CVT     288
#define CVT_TOTAL  4447396
#define WS_W1T     4447696
#define WS_W2T     4521424
#define WS_OFF     4668880
#define WS_Y1      5848528
#define WS_Y2      14237136

struct SrcPtrs { const void* p[13]; };

__global__ void probe_dtype_k(const unsigned int* __restrict__ g1, int* __restrict__ flag) {
    if (threadIdx.x == 0 && blockIdx.x == 0) {
        flag[0] = ((g1[0] & 0xFFFFu) != 0u) ? 1 : 0;  // fp32 1.0f -> low16==0 ; bf16 pair -> 0x3F80
    }
}

__global__ __launch_bounds__(256) void convert_inputs_k(SrcPtrs sp, float* __restrict__ dst,
                                                        const int* __restrict__ flag, int total) {
    int i = blockIdx.x * 256 + threadIdx.x;
    if (i >= total) return;
    constexpr int prefix[13] = {0, 4194304, 4204672, 4204690, 4278418, 4278546, 4278674,
                                4278802, 4299538, 4299556, 4447012, 4447140, 4447268};
    const void* src = sp.p[0];
    int base = 0;
#pragma unroll
    for (int q = 1; q < 13; ++q) {
        if (i >= prefix[q]) { src = sp.p[q]; base = prefix[q]; }
    }
    int local = i - base;
    float v;
    if (flag[0] != 0) {
        unsigned short u = ((const unsigned short*)src)[local];
        unsigned int bits = ((unsigned int)u) << 16;
        v = __uint_as_float(bits);
    } else {
        v = ((const float*)src)[local];
    }
    dst[i] = v;
}

// wt[(ci*9+k)*128 + o] = w[o][ci][k]   (CO must be 128)
__global__ __launch_bounds__(256) void transpose_w_k(const float* __restrict__ w, float* __restrict__ wt, int cin) {
    int i = blockIdx.x * 256 + threadIdx.x;
    int total = cin * 9 * 128;
    if (i >= total) return;
    int o  = i & 127;
    int ck = i >> 7;
    wt[i] = w[o * cin * 9 + ck];
}

// Direct conv3x3, pad=1, CO=18. Block = 2 h-rows x 128 w, co uniform per block.
__global__ __launch_bounds__(256) void conv3x3_k(const float* __restrict__ x, const float* __restrict__ w,
                                                 const float* __restrict__ bias, float* __restrict__ out, int cin) {
    int bi = blockIdx.x;
    int hb = bi & 63;
    int co = (bi >> 6) % KOFF;
    int b  = bi / (64 * KOFF);
    int t  = threadIdx.x;
    int wq = t & 127;
    int h  = hb * 2 + (t >> 7);
    float acc = bias[co];
    const float* wco = w + co * cin * 9;
    for (int ci = 0; ci < cin; ++ci) {
        const float* plane = x + ((long)(b * cin + ci) << 14);
        const float* wk = wco + ci * 9;
        float k0 = wk[0], k1 = wk[1], k2 = wk[2];
        float k3 = wk[3], k4 = wk[4], k5 = wk[5];
        float k6 = wk[6], k7 = wk[7], k8 = wk[8];
        int y0 = h - 1, y1 = h, y2 = h + 1;
        float l, c, r;
        if (y0 >= 0) {
            const float* row = plane + (y0 << 7);
            l = (wq > 0)   ? row[wq - 1] : 0.f;
            c = row[wq];
            r = (wq < 127) ? row[wq + 1] : 0.f;
            acc += l * k0 + c * k1 + r * k2;
        }
        {
            const float* row = plane + (y1 << 7);
            l = (wq > 0)   ? row[wq - 1] : 0.f;
            c = row[wq];
            r = (wq < 127) ? row[wq + 1] : 0.f;
            acc += l * k3 + c * k4 + r * k5;
        }
        if (y2 < H_) {
            const float* row = plane + (y2 << 7);
            l = (wq > 0)   ? row[wq - 1] : 0.f;
            c = row[wq];
            r = (wq < 127) ? row[wq + 1] : 0.f;
            acc += l * k6 + c * k7 + r * k8;
        }
    }
    out[((long)(b * KOFF + co) << 14) + (h << 7) + wq] = acc;
}

// Deformable conv: block = 16 pixels (one b,h, 16 consecutive w) x all 128 co.
template <int CIN>
__global__ __launch_bounds__(256) void deform_k(const float* __restrict__ x, const float* __restrict__ off,
                                                const float* __restrict__ wt, const float* __restrict__ bias,
                                                float* __restrict__ out) {
    __shared__ float s_samp[64 * 144];          // [ci_local*9+k][p] 36 KB
    __shared__ float s_w00[144], s_w01[144], s_w10[144], s_w11[144];
    __shared__ int   s_i00[144], s_i01[144], s_i10[144], s_i11[144];

    int bi = blockIdx.x;
    int w0 = (bi & 7) * 16;
    int h  = (bi >> 3) & 127;
    int b  = bi >> 10;
    int t  = threadIdx.x;

    if (t < 144) {
        int p = t & 15;
        int k = t >> 4;
        int wpix = w0 + p;
        long obase = ((long)(b * KOFF) << 14) + (h << 7) + wpix;
        float oy = off[obase + ((long)(2 * k) << 14)];
        float ox = off[obase + ((long)(2 * k + 1) << 14)];
        float py = (float)(h - 1 + (k / 3)) + oy;
        float px = (float)(wpix - 1 + (k % 3)) + ox;
        float fy = floorf(py), fx = floorf(px);
        float wy = py - fy, wx = px - fx;
        int y0 = (int)fy, x0 = (int)fx;
        int y1 = y0 + 1, x1 = x0 + 1;
        bool vy0 = (y0 >= 0) && (y0 < H_);
        bool vy1 = (y1 >= 0) && (y1 < H_);
        bool vx0 = (x0 >= 0) && (x0 < W_);
        bool vx1 = (x1 >= 0) && (x1 < W_);
        float wy0 = 1.f - wy, wx0 = 1.f - wx;
        s_w00[t] = (vy0 && vx0) ? wy0 * wx0 : 0.f;
        s_w01[t] = (vy0 && vx1) ? wy0 * wx  : 0.f;
        s_w10[t] = (vy1 && vx0) ? wy  * wx0 : 0.f;
        s_w11[t] = (vy1 && vx1) ? wy  * wx  : 0.f;
        int iy0 = min(max(y0, 0), H_ - 1), iy1 = min(max(y1, 0), H_ - 1);
        int ix0 = min(max(x0, 0), W_ - 1), ix1 = min(max(x1, 0), W_ - 1);
        s_i00[t] = iy0 * W_ + ix0;
        s_i01[t] = iy0 * W_ + ix1;
        s_i10[t] = iy1 * W_ + ix0;
        s_i11[t] = iy1 * W_ + ix1;
    }

    int co = t & 127;
    int pg = t >> 7;
    float bv = bias[co];
    float acc[8];
#pragma unroll
    for (int j = 0; j < 8; ++j) acc[j] = bv;

    constexpr int CHUNKS = CIN / 64;
    for (int ch = 0; ch < CHUNKS; ++ch) {
        __syncthreads();
        // phase 1: gather 64 ci x 144 (k,p) samples into LDS
        for (int i = t; i < 64 * 144; i += 256) {
            int cil = i / 144;
            int r   = i - cil * 144;
            const float* plane = x + ((long)(b * CIN + ch * 64 + cil) << 14);
            float s = s_w00[r] * plane[s_i00[r]]
                    + s_w01[r] * plane[s_i01[r]]
                    + s_w10[r] * plane[s_i10[r]]
                    + s_w11[r] * plane[s_i11[r]];
            s_samp[i] = s;
        }
        __syncthreads();
        // phase 2: acc[co][p] += sampled[ck][p] * wt[ck][co]
        const float* wtc = wt + (ch * 576) * 128 + co;
#pragma unroll 4
        for (int ckl = 0; ckl < 576; ++ckl) {
            float wv = wtc[ckl * 128];
            const float4* sp4 = reinterpret_cast<const float4*>(&s_samp[ckl * 16 + pg * 8]);
            float4 a0 = sp4[0];
            float4 a1 = sp4[1];
            acc[0] += a0.x * wv; acc[1] += a0.y * wv; acc[2] += a0.z * wv; acc[3] += a0.w * wv;
            acc[4] += a1.x * wv; acc[5] += a1.y * wv; acc[6] += a1.z * wv; acc[7] += a1.w * wv;
        }
    }

    long ob = ((long)(b * 128 + co) << 14) + (h << 7) + w0 + pg * 8;
#pragma unroll
    for (int j = 0; j < 8; ++j) out[ob + j] = acc[j];
}

__global__ __launch_bounds__(256) void bn_stats_k(const float* __restrict__ y, const float* __restrict__ g,
                                                  const float* __restrict__ be, float* __restrict__ ab) {
    int c = blockIdx.x;
    int t = threadIdx.x;
    float sum = 0.f, ss = 0.f;
    for (int i = t; i < BB * HWP; i += 256) {
        int bq = i >> 14;
        int hw = i & (HWP - 1);
        float v = y[((long)(bq * 128 + c) << 14) + hw];
        sum += v; ss += v * v;
    }
#pragma unroll
    for (int o = 32; o > 0; o >>= 1) { sum += __shfl_down(sum, o); ss += __shfl_down(ss, o); }
    __shared__ float s1[4], s2[4];
    int wave = t >> 6;
    if ((t & 63) == 0) { s1[wave] = sum; s2[wave] = ss; }
    __syncthreads();
    if (t == 0) {
        sum = s1[0] + s1[1] + s1[2] + s1[3];
        ss  = s2[0] + s2[1] + s2[2] + s2[3];
        float mean = sum * (1.f / 65536.f);
        float var  = ss  * (1.f / 65536.f) - mean * mean;
        float inv  = rsqrtf(var + 1e-5f);
        float a = g[c] * inv;
        ab[c]       = a;
        ab[128 + c] = be[c] - mean * a;
    }
}

__global__ __launch_bounds__(256) void bn_apply_k(float* __restrict__ y, const float* __restrict__ ab, int total4) {
    int i = blockIdx.x * 256 + threadIdx.x;
    if (i >= total4) return;
    int c = (i >> 12) & 127;
    float a = ab[c], sh = ab[128 + c];
    float4 v = reinterpret_cast<float4*>(y)[i];
    v.x = fmaxf(v.x * a + sh, 0.f);
    v.y = fmaxf(v.y * a + sh, 0.f);
    v.z = fmaxf(v.z * a + sh, 0.f);
    v.w = fmaxf(v.w * a + sh, 0.f);
    reinterpret_cast<float4*>(y)[i] = v;
}

__global__ __launch_bounds__(256) void bn_apply_out_k(const float* __restrict__ y, const float* __restrict__ ab,
                                                      const int* __restrict__ flag, void* __restrict__ out, int total4) {
    int i = blockIdx.x * 256 + threadIdx.x;
    if (i >= total4) return;
    int c = (i >> 12) & 127;
    float a = ab[c], sh = ab[128 + c];
    float4 v = reinterpret_cast<const float4*>(y)[i];
    v.x = fmaxf(v.x * a + sh, 0.f);
    v.y = fmaxf(v.y * a + sh, 0.f);
    v.z = fmaxf(v.z * a + sh, 0.f);
    v.w = fmaxf(v.w * a + sh, 0.f);
    if (flag[0] != 0) {
        __hip_bfloat16 b0 = __float2bfloat16(v.x);
        __hip_bfloat16 b1 = __float2bfloat16(v.y);
        __hip_bfloat16 b2 = __float2bfloat16(v.z);
        __hip_bfloat16 b3 = __float2bfloat16(v.w);
        ushort4 u;
        u.x = *reinterpret_cast<unsigned short*>(&b0);
        u.y = *reinterpret_cast<unsigned short*>(&b1);
        u.z = *reinterpret_cast<unsigned short*>(&b2);
        u.w = *reinterpret_cast<unsigned short*>(&b3);
        reinterpret_cast<ushort4*>(out)[i] = u;
    } else {
        reinterpret_cast<float4*>(out)[i] = v;
    }
}

extern "C" void kernel_launch(void* const* d_in, const int* in_sizes, int n_in,
                              void* d_out, int out_size, void* d_ws, size_t ws_size,
                              hipStream_t stream) {
    float* ws   = (float*)d_ws;
    int*   flag = (int*)d_ws;
    float* ab   = ws + WS_AB;
    float* cvt  = ws + WS_CVT;

    const float* X     = cvt + 0;
    const float* Woff1 = cvt + 4194304;
    const float* Boff1 = cvt + 4204672;
    const float* W1f   = cvt + 4204690;
    const float* B1f   = cvt + 4278418;
    const float* G1    = cvt + 4278546;
    const float* Be1   = cvt + 4278674;
    const float* Woff2 = cvt + 4278802;
    const float* Boff2 = cvt + 4299538;
    const float* W2f   = cvt + 4299556;
    const float* B2f   = cvt + 4447012;
    const float* G2    = cvt + 4447140;
    const float* Be2   = cvt + 4447268;

    float* W1T = ws + WS_W1T;
    float* W2T = ws + WS_W2T;
    float* OFF = ws + WS_OFF;
    float* Y1  = ws + WS_Y1;
    float* Y2  = ws + WS_Y2;

    SrcPtrs sp;
    for (int j = 0; j < 13; ++j) sp.p[j] = d_in[j];

    probe_dtype_k<<<1, 64, 0, stream>>>((const unsigned int*)d_in[5], flag);
    convert_inputs_k<<<(CVT_TOTAL + 255) / 256, 256, 0, stream>>>(sp, cvt, flag, CVT_TOTAL);
    transpose_w_k<<<(64 * 9 * 128 + 255) / 256, 256, 0, stream>>>(W1f, W1T, 64);
    transpose_w_k<<<(128 * 9 * 128 + 255) / 256, 256, 0, stream>>>(W2f, W2T, 128);

    // stage 1
    conv3x3_k<<<BB * KOFF * 64, 256, 0, stream>>>(X, Woff1, Boff1, OFF, CIN1);
    deform_k<64><<<BB * 128 * 8, 256, 0, stream>>>(X, OFF, W1T, B1f, Y1);
    bn_stats_k<<<128, 256, 0, stream>>>(Y1, G1, Be1, ab);
    bn_apply_k<<<(BB * 128 * HWP / 4 + 255) / 256, 256, 0, stream>>>(Y1, ab, BB * 128 * HWP / 4);

    // stage 2
    conv3x3_k<<<BB * KOFF * 64, 256, 0, stream>>>(Y1, Woff2, Boff2, OFF, CMID);
    deform_k<128><<<BB * 128 * 8, 256, 0, stream>>>(Y1, OFF, W2T, B2f, Y2);
    bn_stats_k<<<128, 256, 0, stream>>>(Y2, G2, Be2, ab);
    bn_apply_out_k<<<(BB * 128 * HWP / 4 + 255) / 256, 256, 0, stream>>>(Y2, ab, flag, d_out, BB * 128 * HWP / 4);
}

// Round 2
// 864.651 us; speedup vs baseline: 1.7597x; 1.7597x over previous
//
#include <hip/hip_runtime.h>
#include <hip/hip_bf16.h>

#define BB 4
#define H_ 128
#define W_ 128
#define HWP 16384
#define CIN1 64
#define CMID 128
#define KOFF 18

typedef short short8 __attribute__((ext_vector_type(8)));
typedef float floatx4 __attribute__((ext_vector_type(4)));

// ---- workspace layout (float offsets) ----
#define WS_AB   16
#define WS_CVT  288
#define CVT_TOTAL 4447396
#define WS_WF1  4447744
#define WS_WF2  4484608
#define WS_XT   4558336
#define WS_OFF  6655488
#define WS_Y1   7835136
#define WS_Y1T  16223744
#define WS_Y2   WS_Y1      // Y1 (fp32 NCHW) is dead after conv2; alias

// cvt-relative input offsets
#define R_X     0
#define R_WOFF1 4194304
#define R_BOFF1 4204672
#define R_W1    4204690
#define R_B1    4278418
#define R_G1    4278546
#define R_BE1   4278674
#define R_WOFF2 4278802
#define R_BOFF2 4299538
#define R_W2    4299556
#define R_B2    4447012
#define R_G2    4447140
#define R_BE2   4447268

struct SrcPtrs { const void* p[13]; };

__device__ inline short f2bf(float f) {
    __hip_bfloat16 h = __float2bfloat16(f);
    return *reinterpret_cast<short*>(&h);
}
__device__ inline float bf2f(unsigned short u) {
    return __uint_as_float(((unsigned int)u) << 16);
}

__global__ void probe_dtype_k(const unsigned int* __restrict__ g1, int* __restrict__ flag) {
    if (threadIdx.x == 0 && blockIdx.x == 0) {
        flag[0] = ((g1[0] & 0xFFFFu) != 0u) ? 1 : 0;
    }
}

__global__ __launch_bounds__(256) void convert_inputs_k(SrcPtrs sp, float* __restrict__ dst,
                                                        const int* __restrict__ flag, int total) {
    int i = blockIdx.x * 256 + threadIdx.x;
    if (i >= total) return;
    constexpr int prefix[13] = {0, R_WOFF1, R_BOFF1, R_W1, R_B1, R_G1, R_BE1,
                                R_WOFF2, R_BOFF2, R_W2, R_B2, R_G2, R_BE2};
    const void* src = sp.p[0];
    int base = 0;
#pragma unroll
    for (int q = 1; q < 13; ++q) {
        if (i >= prefix[q]) { src = sp.p[q]; base = prefix[q]; }
    }
    int local = i - base;
    float v;
    if (flag[0] != 0) {
        v = bf2f(((const unsigned short*)src)[local]);
    } else {
        v = ((const float*)src)[local];
    }
    dst[i] = v;
}

// Pack conv weights into MFMA A-fragment order.
// wf element idx: j=idx&7, lane=(idx>>3)&63, rem=idx>>9, ks=rem%KSTEPS, ct=rem/KSTEPS
// A[m][k]: m = ct*16+(lane&15), k = ks*32+(lane>>4)*8+j ; k = ci*9+kk
template <int CIN>
__global__ __launch_bounds__(256) void wf_build_k(const float* __restrict__ w, short* __restrict__ wf) {
    constexpr int KSTEPS = CIN * 9 / 32;
    int idx = blockIdx.x * 256 + threadIdx.x;
    int j    = idx & 7;
    int lane = (idx >> 3) & 63;
    int rem  = idx >> 9;
    int ks   = rem % KSTEPS;
    int ct   = rem / KSTEPS;
    int co = ct * 16 + (lane & 15);
    int k  = ks * 32 + (lane >> 4) * 8 + j;
    int ci = k / 9;
    int kk = k - ci * 9;
    wf[idx] = f2bf(w[(co * CIN + ci) * 9 + kk]);
}

// X (fp32 NCHW, C=64) -> XT (bf16 NHWC) via LDS tile transpose
__global__ __launch_bounds__(256) void xt_build_k(const float* __restrict__ x, unsigned short* __restrict__ xt) {
    __shared__ __align__(4) short s_t[64 * 66];
    int bi  = blockIdx.x;           // 4 * 256
    int hw0 = (bi & 255) * 64;
    int b   = bi >> 8;
    int t   = threadIdx.x;
    int hwp = t & 63;
#pragma unroll
    for (int it = 0; it < 16; ++it) {
        int c = it * 4 + (t >> 6);
        float v = x[((long)(b * 64 + c) << 14) + hw0 + hwp];
        s_t[hwp * 66 + c] = f2bf(v);
    }
    __syncthreads();
#pragma unroll
    for (int it = 0; it < 8; ++it) {
        int i  = it * 256 + t;
        int c2 = (i & 31) * 2;
        int hw2 = i >> 5;
        int sv = *(const int*)&s_t[hw2 * 66 + c2];
        *(int*)&xt[((long)((b << 14) + hw0 + hw2)) * 64 + c2] = sv;
    }
}

// Direct conv3x3, pad=1, CO=18 (offset conv) — fp32 NCHW
__global__ __launch_bounds__(256) void conv3x3_k(const float* __restrict__ x, const float* __restrict__ w,
                                                 const float* __restrict__ bias, float* __restrict__ out, int cin) {
    int bi = blockIdx.x;
    int hb = bi & 63;
    int co = (bi >> 6) % KOFF;
    int b  = bi / (64 * KOFF);
    int t  = threadIdx.x;
    int wq = t & 127;
    int h  = hb * 2 + (t >> 7);
    float acc = bias[co];
    const float* wco = w + co * cin * 9;
    for (int ci = 0; ci < cin; ++ci) {
        const float* plane = x + ((long)(b * cin + ci) << 14);
        const float* wk = wco + ci * 9;
        float k0 = wk[0], k1 = wk[1], k2 = wk[2];
        float k3 = wk[3], k4 = wk[4], k5 = wk[5];
        float k6 = wk[6], k7 = wk[7], k8 = wk[8];
        int y0 = h - 1, y2 = h + 1;
        float l, c, r;
        if (y0 >= 0) {
            const float* row = plane + (y0 << 7);
            l = (wq > 0)   ? row[wq - 1] : 0.f;
            c = row[wq];
            r = (wq < 127) ? row[wq + 1] : 0.f;
            acc += l * k0 + c * k1 + r * k2;
        }
        {
            const float* row = plane + (h << 7);
            l = (wq > 0)   ? row[wq - 1] : 0.f;
            c = row[wq];
            r = (wq < 127) ? row[wq + 1] : 0.f;
            acc += l * k3 + c * k4 + r * k5;
        }
        if (y2 < H_) {
            const float* row = plane + (y2 << 7);
            l = (wq > 0)   ? row[wq - 1] : 0.f;
            c = row[wq];
            r = (wq < 127) ? row[wq + 1] : 0.f;
            acc += l * k6 + c * k7 + r * k8;
        }
    }
    out[((long)(b * KOFF + co) << 14) + (h << 7) + wq] = acc;
}

// Deform conv via MFMA. Block: 16 pixels x 128 co. xt is bf16 NHWC.
template <int CIN>
__global__ __launch_bounds__(256) void deform_mfma_k(const unsigned short* __restrict__ xt,
                                                     const float* __restrict__ off,
                                                     const short* __restrict__ wf,
                                                     const float* __restrict__ bias,
                                                     float* __restrict__ out) {
    constexpr int CHUNKS = CIN / 64;
    constexpr int KSTEPS = CHUNKS * 18;
    __shared__ __align__(16) short s_samp[16 * 584];   // [p][k_local], pad 576->584
    __shared__ __align__(16) float s_tw[144][4];       // bilinear weights per (p,kk)
    __shared__ __align__(16) int   s_tp[144][4];       // corner pixel indices per (p,kk)

    int bi = blockIdx.x;
    int w0 = (bi & 7) * 16;
    int h  = (bi >> 3) & 127;
    int b  = bi >> 10;
    int t  = threadIdx.x;

    if (t < 144) {
        int p = t & 15;
        int k = t >> 4;
        int wpix = w0 + p;
        long obase = ((long)(b * KOFF) << 14) + (h << 7) + wpix;
        float oy = off[obase + ((long)(2 * k) << 14)];
        float ox = off[obase + ((long)(2 * k + 1) << 14)];
        float py = (float)(h - 1 + (k / 3)) + oy;
        float px = (float)(wpix - 1 + (k % 3)) + ox;
        float fy = floorf(py), fx = floorf(px);
        float wy = py - fy, wx = px - fx;
        int y0 = (int)fy, x0 = (int)fx;
        int y1 = y0 + 1, x1 = x0 + 1;
        bool vy0 = (y0 >= 0) && (y0 < H_);
        bool vy1 = (y1 >= 0) && (y1 < H_);
        bool vx0 = (x0 >= 0) && (x0 < W_);
        bool vx1 = (x1 >= 0) && (x1 < W_);
        float wy0 = 1.f - wy, wx0 = 1.f - wx;
        s_tw[t][0] = (vy0 && vx0) ? wy0 * wx0 : 0.f;
        s_tw[t][1] = (vy0 && vx1) ? wy0 * wx  : 0.f;
        s_tw[t][2] = (vy1 && vx0) ? wy  * wx0 : 0.f;
        s_tw[t][3] = (vy1 && vx1) ? wy  * wx  : 0.f;
        int iy0 = min(max(y0, 0), H_ - 1), iy1 = min(max(y1, 0), H_ - 1);
        int ix0 = min(max(x0, 0), W_ - 1), ix1 = min(max(x1, 0), W_ - 1);
        s_tp[t][0] = iy0 * W_ + ix0;
        s_tp[t][1] = iy0 * W_ + ix1;
        s_tp[t][2] = iy1 * W_ + ix0;
        s_tp[t][3] = iy1 * W_ + ix1;
    }

    int lane = t & 63;
    int wv   = t >> 6;
    int p_   = lane & 15;
    int quad = lane >> 4;
    int ct0 = wv * 2, ct1 = wv * 2 + 1;

    floatx4 acc0, acc1;
#pragma unroll
    for (int r = 0; r < 4; ++r) {
        acc0[r] = bias[ct0 * 16 + quad * 4 + r];
        acc1[r] = bias[ct1 * 16 + quad * 4 + r];
    }

    const unsigned short* xb = xt + (long)b * HWP * CIN + lane;

    for (int ch = 0; ch < CHUNKS; ++ch) {
        __syncthreads();   // table ready / previous MFMA reads of s_samp done
        const unsigned short* xc = xb + ch * 64;
        for (int r = wv; r < 144; r += 4) {
            floatx4 wv4 = *(const floatx4*)s_tw[r];
            int4 pv4 = *(const int4*)s_tp[r];
            float v = wv4[0] * bf2f(xc[pv4.x * CIN])
                    + wv4[1] * bf2f(xc[pv4.y * CIN])
                    + wv4[2] * bf2f(xc[pv4.z * CIN])
                    + wv4[3] * bf2f(xc[pv4.w * CIN]);
            s_samp[(r & 15) * 584 + lane * 9 + (r >> 4)] = f2bf(v);
        }
        __syncthreads();
#pragma unroll 2
        for (int ks = 0; ks < 18; ++ks) {
            int ksg = ch * 18 + ks;
            short8 bfrag = *(const short8*)&s_samp[p_ * 584 + ks * 32 + quad * 8];
            short8 a0 = *(const short8*)&wf[(((long)ct0 * KSTEPS + ksg) * 64 + lane) * 8];
            short8 a1 = *(const short8*)&wf[(((long)ct1 * KSTEPS + ksg) * 64 + lane) * 8];
            acc0 = __builtin_amdgcn_mfma_f32_16x16x32_bf16(a0, bfrag, acc0, 0, 0, 0);
            acc1 = __builtin_amdgcn_mfma_f32_16x16x32_bf16(a1, bfrag, acc1, 0, 0, 0);
        }
    }

    long ob = ((long)(b * 128) << 14) + (h << 7) + w0 + p_;
#pragma unroll
    for (int r = 0; r < 4; ++r) {
        out[ob + ((long)(ct0 * 16 + quad * 4 + r) << 14)] = acc0[r];
        out[ob + ((long)(ct1 * 16 + quad * 4 + r) << 14)] = acc1[r];
    }
}

__global__ __launch_bounds__(256) void bn_stats_k(const float* __restrict__ y, const float* __restrict__ g,
                                                  const float* __restrict__ be, float* __restrict__ ab) {
    int c = blockIdx.x;
    int t = threadIdx.x;
    float sum = 0.f, ss = 0.f;
    for (int i = t; i < BB * HWP; i += 256) {
        int bq = i >> 14;
        int hw = i & (HWP - 1);
        float v = y[((long)(bq * 128 + c) << 14) + hw];
        sum += v; ss += v * v;
    }
#pragma unroll
    for (int o = 32; o > 0; o >>= 1) { sum += __shfl_down(sum, o); ss += __shfl_down(ss, o); }
    __shared__ float s1[4], s2[4];
    int wave = t >> 6;
    if ((t & 63) == 0) { s1[wave] = sum; s2[wave] = ss; }
    __syncthreads();
    if (t == 0) {
        sum = s1[0] + s1[1] + s1[2] + s1[3];
        ss  = s2[0] + s2[1] + s2[2] + s2[3];
        float mean = sum * (1.f / 65536.f);
        float var  = ss  * (1.f / 65536.f) - mean * mean;
        float inv  = rsqrtf(var + 1e-5f);
        float a = g[c] * inv;
        ab[c]       = a;
        ab[128 + c] = be[c] - mean * a;
    }
}

// BN+ReLU in-place on fp32 NCHW, plus transposed bf16 NHWC copy for the next gather
__global__ __launch_bounds__(256) void bn_apply_dual_k(float* __restrict__ y, const float* __restrict__ ab,
                                                       unsigned short* __restrict__ yt) {
    __shared__ __align__(4) short s_t[64 * 134];
    int bi  = blockIdx.x;          // 4 * 256
    int hw0 = (bi & 255) * 64;
    int b   = bi >> 8;
    int t   = threadIdx.x;
    int hwp = t & 63;
#pragma unroll 4
    for (int it = 0; it < 32; ++it) {
        int c = it * 4 + (t >> 6);
        float a = ab[c], sh = ab[128 + c];
        long addr = ((long)(b * 128 + c) << 14) + hw0 + hwp;
        float v = y[addr];
        v = fmaxf(v * a + sh, 0.f);
        y[addr] = v;
        s_t[hwp * 134 + c] = f2bf(v);
    }
    __syncthreads();
#pragma unroll 4
    for (int it = 0; it < 16; ++it) {
        int i   = it * 256 + t;
        int c2  = (i & 63) * 2;
        int hw2 = i >> 6;
        int sv = *(const int*)&s_t[hw2 * 134 + c2];
        *(int*)&yt[((long)((b << 14) + hw0 + hw2)) * 128 + c2] = sv;
    }
}

__global__ __launch_bounds__(256) void bn_apply_out_k(const float* __restrict__ y, const float* __restrict__ ab,
                                                      const int* __restrict__ flag, void* __restrict__ out, int total4) {
    int i = blockIdx.x * 256 + threadIdx.x;
    if (i >= total4) return;
    int c = (i >> 12) & 127;
    float a = ab[c], sh = ab[128 + c];
    float4 v = reinterpret_cast<const float4*>(y)[i];
    v.x = fmaxf(v.x * a + sh, 0.f);
    v.y = fmaxf(v.y * a + sh, 0.f);
    v.z = fmaxf(v.z * a + sh, 0.f);
    v.w = fmaxf(v.w * a + sh, 0.f);
    if (flag[0] != 0) {
        ushort4 u;
        u.x = (unsigned short)f2bf(v.x);
        u.y = (unsigned short)f2bf(v.y);
        u.z = (unsigned short)f2bf(v.z);
        u.w = (unsigned short)f2bf(v.w);
        reinterpret_cast<ushort4*>(out)[i] = u;
    } else {
        reinterpret_cast<float4*>(out)[i] = v;
    }
}

extern "C" void kernel_launch(void* const* d_in, const int* in_sizes, int n_in,
                              void* d_out, int out_size, void* d_ws, size_t ws_size,
                              hipStream_t stream) {
    float* ws   = (float*)d_ws;
    int*   flag = (int*)d_ws;
    float* ab   = ws + WS_AB;
    float* cvt  = ws + WS_CVT;

    const float* X     = cvt + R_X;
    const float* Woff1 = cvt + R_WOFF1;
    const float* Boff1 = cvt + R_BOFF1;
    const float* W1f   = cvt + R_W1;
    const float* B1f   = cvt + R_B1;
    const float* G1    = cvt + R_G1;
    const float* Be1   = cvt + R_BE1;
    const float* Woff2 = cvt + R_WOFF2;
    const float* Boff2 = cvt + R_BOFF2;
    const float* W2f   = cvt + R_W2;
    const float* B2f   = cvt + R_B2;
    const float* G2    = cvt + R_G2;
    const float* Be2   = cvt + R_BE2;

    short* WF1 = (short*)(ws + WS_WF1);
    short* WF2 = (short*)(ws + WS_WF2);
    unsigned short* XT  = (unsigned short*)(ws + WS_XT);
    unsigned short* Y1T = (unsigned short*)(ws + WS_Y1T);
    float* OFF = ws + WS_OFF;
    float* Y1  = ws + WS_Y1;
    float* Y2  = ws + WS_Y2;   // aliases Y1 (Y1 fp32 dead after conv2)

    SrcPtrs sp;
    for (int j = 0; j < 13; ++j) sp.p[j] = d_in[j];

    probe_dtype_k<<<1, 64, 0, stream>>>((const unsigned int*)d_in[5], flag);
    convert_inputs_k<<<(CVT_TOTAL + 255) / 256, 256, 0, stream>>>(sp, cvt, flag, CVT_TOTAL);
    wf_build_k<64><<<288, 256, 0, stream>>>(W1f, WF1);
    wf_build_k<128><<<576, 256, 0, stream>>>(W2f, WF2);
    xt_build_k<<<1024, 256, 0, stream>>>(X, XT);

    // stage 1
    conv3x3_k<<<BB * KOFF * 64, 256, 0, stream>>>(X, Woff1, Boff1, OFF, CIN1);
    deform_mfma_k<64><<<BB * 128 * 8, 256, 0, stream>>>(XT, OFF, WF1, B1f, Y1);
    bn_stats_k<<<128, 256, 0, stream>>>(Y1, G1, Be1, ab);
    bn_apply_dual_k<<<1024, 256, 0, stream>>>(Y1, ab, Y1T);

    // stage 2
    conv3x3_k<<<BB * KOFF * 64, 256, 0, stream>>>(Y1, Woff2, Boff2, OFF, CMID);
    deform_mfma_k<128><<<BB * 128 * 8, 256, 0, stream>>>(Y1T, OFF, WF2, B2f, Y2);
    bn_stats_k<<<128, 256, 0, stream>>>(Y2, G2, Be2, ab);
    bn_apply_out_k<<<(BB * 128 * HWP / 4 + 255) / 256, 256, 0, stream>>>(Y2, ab, flag, d_out, BB * 128 * HWP / 4);
}

// Round 3
// 737.466 us; speedup vs baseline: 2.0632x; 1.1725x over previous
//
#include <hip/hip_runtime.h>
#include <hip/hip_bf16.h>

#define BB 4
#define H_ 128
#define W_ 128
#define HWP 16384
#define CIN1 64
#define CMID 128
#define KOFF 18

typedef short short8 __attribute__((ext_vector_type(8)));
typedef float floatx4 __attribute__((ext_vector_type(4)));

// ---- workspace layout (float offsets) ----
#define WS_AB   16
#define WS_CVT  288
#define CVT_TOTAL 4447396
#define WS_WF1  4447744
#define WS_WF2  4484608
#define WS_XT   4558336
#define WS_OFF  6655488
#define WS_Y1   7835136
#define WS_Y1T  16223744
#define WS_Y2   WS_Y1      // Y1 (fp32 NCHW) is dead after conv2; alias

// cvt-relative input offsets
#define R_X     0
#define R_WOFF1 4194304
#define R_BOFF1 4204672
#define R_W1    4204690
#define R_B1    4278418
#define R_G1    4278546
#define R_BE1   4278674
#define R_WOFF2 4278802
#define R_BOFF2 4299538
#define R_W2    4299556
#define R_B2    4447012
#define R_G2    4447140
#define R_BE2   4447268

struct SrcPtrs { const void* p[13]; };

__device__ inline short f2bf(float f) {
    __hip_bfloat16 h = __float2bfloat16(f);
    return *reinterpret_cast<short*>(&h);
}
__device__ inline float bf2f(unsigned short u) {
    return __uint_as_float(((unsigned int)u) << 16);
}

__global__ void probe_dtype_k(const unsigned int* __restrict__ g1, int* __restrict__ flag) {
    if (threadIdx.x == 0 && blockIdx.x == 0) {
        flag[0] = ((g1[0] & 0xFFFFu) != 0u) ? 1 : 0;
    }
}

__global__ __launch_bounds__(256) void convert_inputs_k(SrcPtrs sp, float* __restrict__ dst,
                                                        const int* __restrict__ flag, int total) {
    int i = blockIdx.x * 256 + threadIdx.x;
    if (i >= total) return;
    constexpr int prefix[13] = {0, R_WOFF1, R_BOFF1, R_W1, R_B1, R_G1, R_BE1,
                                R_WOFF2, R_BOFF2, R_W2, R_B2, R_G2, R_BE2};
    const void* src = sp.p[0];
    int base = 0;
#pragma unroll
    for (int q = 1; q < 13; ++q) {
        if (i >= prefix[q]) { src = sp.p[q]; base = prefix[q]; }
    }
    int local = i - base;
    float v;
    if (flag[0] != 0) {
        v = bf2f(((const unsigned short*)src)[local]);
    } else {
        v = ((const float*)src)[local];
    }
    dst[i] = v;
}

// Pack conv weights into MFMA A-fragment order.
template <int CIN>
__global__ __launch_bounds__(256) void wf_build_k(const float* __restrict__ w, short* __restrict__ wf) {
    constexpr int KSTEPS = CIN * 9 / 32;
    int idx = blockIdx.x * 256 + threadIdx.x;
    int j    = idx & 7;
    int lane = (idx >> 3) & 63;
    int rem  = idx >> 9;
    int ks   = rem % KSTEPS;
    int ct   = rem / KSTEPS;
    int co = ct * 16 + (lane & 15);
    int k  = ks * 32 + (lane >> 4) * 8 + j;
    int ci = k / 9;
    int kk = k - ci * 9;
    wf[idx] = f2bf(w[(co * CIN + ci) * 9 + kk]);
}

// X (fp32 NCHW, C=64) -> XT (bf16 NHWC) via LDS tile transpose
__global__ __launch_bounds__(256) void xt_build_k(const float* __restrict__ x, unsigned short* __restrict__ xt) {
    __shared__ __align__(4) short s_t[64 * 66];
    int bi  = blockIdx.x;           // 4 * 256
    int hw0 = (bi & 255) * 64;
    int b   = bi >> 8;
    int t   = threadIdx.x;
    int hwp = t & 63;
#pragma unroll
    for (int it = 0; it < 16; ++it) {
        int c = it * 4 + (t >> 6);
        float v = x[((long)(b * 64 + c) << 14) + hw0 + hwp];
        s_t[hwp * 66 + c] = f2bf(v);
    }
    __syncthreads();
#pragma unroll
    for (int it = 0; it < 8; ++it) {
        int i  = it * 256 + t;
        int c2 = (i & 31) * 2;
        int hw2 = i >> 5;
        int sv = *(const int*)&s_t[hw2 * 66 + c2];
        *(int*)&xt[((long)((b << 14) + hw0 + hw2)) * 64 + c2] = sv;
    }
}

// Offset conv3x3, pad=1, CO=18. One thread = one pixel, ALL 18 co.
// Weights are block-uniform -> s_load; 9 input loads amortize over 162 FMAs.
template <int CIN>
__global__ __launch_bounds__(128) void conv3x3_fast_k(const float* __restrict__ x,
                                                      const float* __restrict__ w,
                                                      const float* __restrict__ bias,
                                                      float* __restrict__ out) {
    int bi = blockIdx.x;        // b*128 + h
    int h  = bi & 127;
    int b  = bi >> 7;
    int wq = threadIdx.x;       // 0..127

    float acc[KOFF];
#pragma unroll
    for (int co = 0; co < KOFF; ++co) acc[co] = bias[co];

    const float* xb = x + ((long)(b * CIN) << 14);
    bool bm = h > 0, bp = h < H_ - 1, bl = wq > 0, br = wq < W_ - 1;
    int rm = (bm ? h - 1 : 0) << 7;
    int rc = h << 7;
    int rp = (bp ? h + 1 : H_ - 1) << 7;

    for (int ci = 0; ci < CIN; ++ci) {
        const float* plane = xb + (ci << 14);
        // unconditional loads at clamped rows (addresses provably inside ws), then select
        float v0 = plane[rm + wq - 1], v1 = plane[rm + wq], v2 = plane[rm + wq + 1];
        float v3 = plane[rc + wq - 1], v4 = plane[rc + wq], v5 = plane[rc + wq + 1];
        float v6 = plane[rp + wq - 1], v7 = plane[rp + wq], v8 = plane[rp + wq + 1];
        v0 = (bm && bl) ? v0 : 0.f;
        v1 = bm ? v1 : 0.f;
        v2 = (bm && br) ? v2 : 0.f;
        v3 = bl ? v3 : 0.f;
        v5 = br ? v5 : 0.f;
        v6 = (bp && bl) ? v6 : 0.f;
        v7 = bp ? v7 : 0.f;
        v8 = (bp && br) ? v8 : 0.f;
        const float* wc = w + ci * 9;
#pragma unroll
        for (int co = 0; co < KOFF; ++co) {
            const float* wk = wc + co * CIN * 9;   // uniform -> SGPR
            acc[co] += v0 * wk[0] + v1 * wk[1] + v2 * wk[2]
                     + v3 * wk[3] + v4 * wk[4] + v5 * wk[5]
                     + v6 * wk[6] + v7 * wk[7] + v8 * wk[8];
        }
    }

    long ob = ((long)(b * KOFF) << 14) + (h << 7) + wq;
#pragma unroll
    for (int co = 0; co < KOFF; ++co) out[ob + ((long)co << 14)] = acc[co];
}

// Deform conv via MFMA. Block: 16 pixels x 128 co. xt is bf16 NHWC.
template <int CIN>
__global__ __launch_bounds__(256) void deform_mfma_k(const unsigned short* __restrict__ xt,
                                                     const float* __restrict__ off,
                                                     const short* __restrict__ wf,
                                                     const float* __restrict__ bias,
                                                     float* __restrict__ out) {
    constexpr int CHUNKS = CIN / 64;
    constexpr int KSTEPS = CHUNKS * 18;
    __shared__ __align__(16) short s_samp[16 * 584];
    __shared__ __align__(16) float s_tw[144][4];
    __shared__ __align__(16) int   s_tp[144][4];

    int bi = blockIdx.x;
    int w0 = (bi & 7) * 16;
    int h  = (bi >> 3) & 127;
    int b  = bi >> 10;
    int t  = threadIdx.x;

    if (t < 144) {
        int p = t & 15;
        int k = t >> 4;
        int wpix = w0 + p;
        long obase = ((long)(b * KOFF) << 14) + (h << 7) + wpix;
        float oy = off[obase + ((long)(2 * k) << 14)];
        float ox = off[obase + ((long)(2 * k + 1) << 14)];
        float py = (float)(h - 1 + (k / 3)) + oy;
        float px = (float)(wpix - 1 + (k % 3)) + ox;
        float fy = floorf(py), fx = floorf(px);
        float wy = py - fy, wx = px - fx;
        int y0 = (int)fy, x0 = (int)fx;
        int y1 = y0 + 1, x1 = x0 + 1;
        bool vy0 = (y0 >= 0) && (y0 < H_);
        bool vy1 = (y1 >= 0) && (y1 < H_);
        bool vx0 = (x0 >= 0) && (x0 < W_);
        bool vx1 = (x1 >= 0) && (x1 < W_);
        float wy0 = 1.f - wy, wx0 = 1.f - wx;
        s_tw[t][0] = (vy0 && vx0) ? wy0 * wx0 : 0.f;
        s_tw[t][1] = (vy0 && vx1) ? wy0 * wx  : 0.f;
        s_tw[t][2] = (vy1 && vx0) ? wy  * wx0 : 0.f;
        s_tw[t][3] = (vy1 && vx1) ? wy  * wx  : 0.f;
        int iy0 = min(max(y0, 0), H_ - 1), iy1 = min(max(y1, 0), H_ - 1);
        int ix0 = min(max(x0, 0), W_ - 1), ix1 = min(max(x1, 0), W_ - 1);
        s_tp[t][0] = iy0 * W_ + ix0;
        s_tp[t][1] = iy0 * W_ + ix1;
        s_tp[t][2] = iy1 * W_ + ix0;
        s_tp[t][3] = iy1 * W_ + ix1;
    }

    int lane = t & 63;
    int wv   = t >> 6;
    int p_   = lane & 15;
    int quad = lane >> 4;
    int ct0 = wv * 2, ct1 = wv * 2 + 1;

    floatx4 acc0, acc1;
#pragma unroll
    for (int r = 0; r < 4; ++r) {
        acc0[r] = bias[ct0 * 16 + quad * 4 + r];
        acc1[r] = bias[ct1 * 16 + quad * 4 + r];
    }

    const unsigned short* xb = xt + (long)b * HWP * CIN + lane;

    for (int ch = 0; ch < CHUNKS; ++ch) {
        __syncthreads();
        const unsigned short* xc = xb + ch * 64;
        for (int r = wv; r < 144; r += 4) {
            floatx4 wv4 = *(const floatx4*)s_tw[r];
            int4 pv4 = *(const int4*)s_tp[r];
            float v = wv4[0] * bf2f(xc[pv4.x * CIN])
                    + wv4[1] * bf2f(xc[pv4.y * CIN])
                    + wv4[2] * bf2f(xc[pv4.z * CIN])
                    + wv4[3] * bf2f(xc[pv4.w * CIN]);
            s_samp[(r & 15) * 584 + lane * 9 + (r >> 4)] = f2bf(v);
        }
        __syncthreads();
#pragma unroll 2
        for (int ks = 0; ks < 18; ++ks) {
            int ksg = ch * 18 + ks;
            short8 bfrag = *(const short8*)&s_samp[p_ * 584 + ks * 32 + quad * 8];
            short8 a0 = *(const short8*)&wf[(((long)ct0 * KSTEPS + ksg) * 64 + lane) * 8];
            short8 a1 = *(const short8*)&wf[(((long)ct1 * KSTEPS + ksg) * 64 + lane) * 8];
            acc0 = __builtin_amdgcn_mfma_f32_16x16x32_bf16(a0, bfrag, acc0, 0, 0, 0);
            acc1 = __builtin_amdgcn_mfma_f32_16x16x32_bf16(a1, bfrag, acc1, 0, 0, 0);
        }
    }

    long ob = ((long)(b * 128) << 14) + (h << 7) + w0 + p_;
#pragma unroll
    for (int r = 0; r < 4; ++r) {
        out[ob + ((long)(ct0 * 16 + quad * 4 + r) << 14)] = acc0[r];
        out[ob + ((long)(ct1 * 16 + quad * 4 + r) << 14)] = acc1[r];
    }
}

__global__ __launch_bounds__(256) void bn_stats_k(const float* __restrict__ y, const float* __restrict__ g,
                                                  const float* __restrict__ be, float* __restrict__ ab) {
    int c = blockIdx.x;
    int t = threadIdx.x;
    float sum = 0.f, ss = 0.f;
    for (int i = t; i < BB * HWP; i += 256) {
        int bq = i >> 14;
        int hw = i & (HWP - 1);
        float v = y[((long)(bq * 128 + c) << 14) + hw];
        sum += v; ss += v * v;
    }
#pragma unroll
    for (int o = 32; o > 0; o >>= 1) { sum += __shfl_down(sum, o); ss += __shfl_down(ss, o); }
    __shared__ float s1[4], s2[4];
    int wave = t >> 6;
    if ((t & 63) == 0) { s1[wave] = sum; s2[wave] = ss; }
    __syncthreads();
    if (t == 0) {
        sum = s1[0] + s1[1] + s1[2] + s1[3];
        ss  = s2[0] + s2[1] + s2[2] + s2[3];
        float mean = sum * (1.f / 65536.f);
        float var  = ss  * (1.f / 65536.f) - mean * mean;
        float inv  = rsqrtf(var + 1e-5f);
        float a = g[c] * inv;
        ab[c]       = a;
        ab[128 + c] = be[c] - mean * a;
    }
}

// BN+ReLU in-place on fp32 NCHW, plus transposed bf16 NHWC copy for the next gather
__global__ __launch_bounds__(256) void bn_apply_dual_k(float* __restrict__ y, const float* __restrict__ ab,
                                                       unsigned short* __restrict__ yt) {
    __shared__ __align__(4) short s_t[64 * 134];
    int bi  = blockIdx.x;          // 4 * 256
    int hw0 = (bi & 255) * 64;
    int b   = bi >> 8;
    int t   = threadIdx.x;
    int hwp = t & 63;
#pragma unroll 4
    for (int it = 0; it < 32; ++it) {
        int c = it * 4 + (t >> 6);
        float a = ab[c], sh = ab[128 + c];
        long addr = ((long)(b * 128 + c) << 14) + hw0 + hwp;
        float v = y[addr];
        v = fmaxf(v * a + sh, 0.f);
        y[addr] = v;
        s_t[hwp * 134 + c] = f2bf(v);
    }
    __syncthreads();
#pragma unroll 4
    for (int it = 0; it < 16; ++it) {
        int i   = it * 256 + t;
        int c2  = (i & 63) * 2;
        int hw2 = i >> 6;
        int sv = *(const int*)&s_t[hw2 * 134 + c2];
        *(int*)&yt[((long)((b << 14) + hw0 + hw2)) * 128 + c2] = sv;
    }
}

__global__ __launch_bounds__(256) void bn_apply_out_k(const float* __restrict__ y, const float* __restrict__ ab,
                                                      const int* __restrict__ flag, void* __restrict__ out, int total4) {
    int i = blockIdx.x * 256 + threadIdx.x;
    if (i >= total4) return;
    int c = (i >> 12) & 127;
    float a = ab[c], sh = ab[128 + c];
    float4 v = reinterpret_cast<const float4*>(y)[i];
    v.x = fmaxf(v.x * a + sh, 0.f);
    v.y = fmaxf(v.y * a + sh, 0.f);
    v.z = fmaxf(v.z * a + sh, 0.f);
    v.w = fmaxf(v.w * a + sh, 0.f);
    if (flag[0] != 0) {
        ushort4 u;
        u.x = (unsigned short)f2bf(v.x);
        u.y = (unsigned short)f2bf(v.y);
        u.z = (unsigned short)f2bf(v.z);
        u.w = (unsigned short)f2bf(v.w);
        reinterpret_cast<ushort4*>(out)[i] = u;
    } else {
        reinterpret_cast<float4*>(out)[i] = v;
    }
}

extern "C" void kernel_launch(void* const* d_in, const int* in_sizes, int n_in,
                              void* d_out, int out_size, void* d_ws, size_t ws_size,
                              hipStream_t stream) {
    float* ws   = (float*)d_ws;
    int*   flag = (int*)d_ws;
    float* ab   = ws + WS_AB;
    float* cvt  = ws + WS_CVT;

    const float* X     = cvt + R_X;
    const float* Woff1 = cvt + R_WOFF1;
    const float* Boff1 = cvt + R_BOFF1;
    const float* W1f   = cvt + R_W1;
    const float* B1f   = cvt + R_B1;
    const float* G1    = cvt + R_G1;
    const float* Be1   = cvt + R_BE1;
    const float* Woff2 = cvt + R_WOFF2;
    const float* Boff2 = cvt + R_BOFF2;
    const float* W2f   = cvt + R_W2;
    const float* B2f   = cvt + R_B2;
    const float* G2    = cvt + R_G2;
    const float* Be2   = cvt + R_BE2;

    short* WF1 = (short*)(ws + WS_WF1);
    short* WF2 = (short*)(ws + WS_WF2);
    unsigned short* XT  = (unsigned short*)(ws + WS_XT);
    unsigned short* Y1T = (unsigned short*)(ws + WS_Y1T);
    float* OFF = ws + WS_OFF;
    float* Y1  = ws + WS_Y1;
    float* Y2  = ws + WS_Y2;

    SrcPtrs sp;
    for (int j = 0; j < 13; ++j) sp.p[j] = d_in[j];

    probe_dtype_k<<<1, 64, 0, stream>>>((const unsigned int*)d_in[5], flag);
    convert_inputs_k<<<(CVT_TOTAL + 255) / 256, 256, 0, stream>>>(sp, cvt, flag, CVT_TOTAL);
    wf_build_k<64><<<288, 256, 0, stream>>>(W1f, WF1);
    wf_build_k<128><<<576, 256, 0, stream>>>(W2f, WF2);
    xt_build_k<<<1024, 256, 0, stream>>>(X, XT);

    // stage 1
    conv3x3_fast_k<64><<<BB * 128, 128, 0, stream>>>(X, Woff1, Boff1, OFF);
    deform_mfma_k<64><<<BB * 128 * 8, 256, 0, stream>>>(XT, OFF, WF1, B1f, Y1);
    bn_stats_k<<<128, 256, 0, stream>>>(Y1, G1, Be1, ab);
    bn_apply_dual_k<<<1024, 256, 0, stream>>>(Y1, ab, Y1T);

    // stage 2
    conv3x3_fast_k<128><<<BB * 128, 128, 0, stream>>>(Y1, Woff2, Boff2, OFF);
    deform_mfma_k<128><<<BB * 128 * 8, 256, 0, stream>>>(Y1T, OFF, WF2, B2f, Y2);
    bn_stats_k<<<128, 256, 0, stream>>>(Y2, G2, Be2, ab);
    bn_apply_out_k<<<(BB * 128 * HWP / 4 + 255) / 256, 256, 0, stream>>>(Y2, ab, flag, d_out, BB * 128 * HWP / 4);
}